// Round 10
// baseline (14.747 us; speedup 1.0000x reference)
//
#include <hip/hip_runtime.h>

#define NS 32
#define NH 32
#define C2L 2.8853900817779268f  // 2*log2(e): e^(2x) = 2^(C2L*x)

// R7's branchless 1-thread/point hot loop, but with BOTH LDS access phases
// conflict-free: unpadded stride-32 [h][s] layouts (hot-loop b64 gather =
// 2-way max = free: distinct s -> distinct bank pairs) and s-fast staging
// decode (per-lane s -> conflict-free transposed writes; the strided global
// gather it causes is a one-time prologue cost). 512 blocks = 2/CU so one
// block's hot loop shadows the other's staging prologue.
__global__ __launch_bounds__(256, 2) void springnn_kernel(
    const float* __restrict__ t_in,
    const float* __restrict__ W1,   // [S][1][H]
    const float* __restrict__ b1,   // [S][H]
    const float* __restrict__ W2,   // [S][H][1]
    const float* __restrict__ b2,   // [S][1]
    float* __restrict__ out,
    int N)
{
    __shared__ float2 w1b1[NH][NS];     // [h][s] = (W1*C2L, b1*C2L)  stride 32
    __shared__ float2 w2p[NH / 2][NS];  // [h2][s] = (-2*W2[2h2], -2*W2[2h2+1])
    __shared__ float  b2eff[NS];        // b2[s] + sum_h W2[s][h] (tanh folding)

    const int tid = threadIdx.x;

    // ---- stage: s-fast decode -> conflict-free LDS writes ----
    #pragma unroll
    for (int it = 0; it < 4; ++it) {
        const int idx = it * 256 + tid;
        const int s = idx & (NS - 1);    // per-lane fast -> LDS bank = s
        const int h = idx >> 5;          // wave-uniform-ish
        w1b1[h][s] = make_float2(W1[s * NH + h] * C2L, b1[s * NH + h] * C2L);
        ((float*)&w2p[h >> 1][s])[h & 1] = -2.0f * W2[s * NH + h];
    }
    if (tid < NS) {
        float acc = b2[tid];
        const float4* w2v = (const float4*)(W2 + tid * NH);
        #pragma unroll
        for (int q = 0; q < NH / 4; ++q) {
            float4 v = w2v[q];
            acc += (v.x + v.y) + (v.z + v.w);
        }
        b2eff[tid] = acc;
    }
    __syncthreads();

    const int n = blockIdx.x * 256 + tid;
    if (n >= N) return;
    const float t = t_in[n];

    // The only segments with w>0 are s0..s0+3 (d = t-s spans (-2,2]).
    const int s0 = (int)ceilf(t - 2.0f);

    float outv = 0.0f;
    #pragma unroll
    for (int j = 0; j < 4; ++j) {
        const int s = s0 + j;
        const bool ok = ((unsigned)s < (unsigned)NS);
        const int sc = ok ? s : 0;                       // clamped: reads unconditional
        // window = (1+cos(pi*d/2))/2 ; v_cos takes revolutions -> arg d/4
        const float c = __builtin_amdgcn_cosf((t - (float)s) * 0.25f);
        const float w = ok ? fmaf(0.5f, c, 0.5f) : 0.0f; // mask folded into weight

        float o0 = b2eff[sc], o1 = 0.0f;                 // 2 chains for ILP
        #pragma unroll
        for (int h2 = 0; h2 < NH / 2; ++h2) {
            const float2 wa = w1b1[2 * h2][sc];
            const float2 wb = w1b1[2 * h2 + 1][sc];
            const float2 wq = w2p[h2][sc];
            const float ea = __builtin_amdgcn_exp2f(fmaf(t, wa.x, wa.y));
            const float eb = __builtin_amdgcn_exp2f(fmaf(t, wb.x, wb.y));
            o0 = fmaf(wq.x, __builtin_amdgcn_rcpf(ea + 1.0f), o0);
            o1 = fmaf(wq.y, __builtin_amdgcn_rcpf(eb + 1.0f), o1);
        }
        outv = fmaf(w, o0 + o1, outv);
    }
    out[n] = outv;
}

extern "C" void kernel_launch(void* const* d_in, const int* in_sizes, int n_in,
                              void* d_out, int out_size, void* d_ws, size_t ws_size,
                              hipStream_t stream) {
    const float* t  = (const float*)d_in[0];
    const float* W1 = (const float*)d_in[1];
    const float* b1 = (const float*)d_in[2];
    const float* W2 = (const float*)d_in[3];
    const float* b2 = (const float*)d_in[4];
    float* outp = (float*)d_out;
    const int N = in_sizes[0];

    const int block = 256;
    const int grid = (N + block - 1) / block;
    springnn_kernel<<<grid, block, 0, stream>>>(t, W1, b1, W2, b2, outp, N);
}

// Round 11
// 11.827 us; speedup vs baseline: 1.2469x; 1.2469x over previous
//
#include <hip/hip_runtime.h>

#define NS 32
#define NH 32
#define M_TAB 4096
#define C2L 2.8853900817779268f               // 2*log2(e): e^(2x) = 2^(C2L*x)
#define STEP (31.0f / (float)M_TAB)
#define INV_STEP ((float)M_TAB / 31.0f)

// Kernel A: tabulate f(t) at M_TAB+1 uniform nodes over [0,31].
// lane = h (32 lanes per grid node, 2 nodes per wave); the 4 segments with
// nonzero cosine window are unrolled, weights read straight from L2-hot global.
__global__ __launch_bounds__(256) void table_kernel(
    const float* __restrict__ W1,   // [S][1][H]
    const float* __restrict__ b1,   // [S][H]
    const float* __restrict__ W2,   // [S][H][1]
    const float* __restrict__ b2,   // [S][1]
    float* __restrict__ table)
{
    const int gid = blockIdx.x * 256 + threadIdx.x;
    const int g = gid >> 5;          // grid node
    const int h = gid & 31;          // hidden unit (lane)
    if (g > M_TAB) return;           // whole half-waves exit together
    const float t = (float)g * STEP;
    const int s0 = (int)ceilf(t - 2.0f);   // segments s0..s0+3 cover all w>0

    float partial = 0.0f;   // sum_j w_j * w2*tanh(.)   (this lane's h)
    float wb2 = 0.0f;       // sum_j w_j * b2[s_j]      (uniform per node)
    #pragma unroll
    for (int j = 0; j < 4; ++j) {
        const int s = s0 + j;
        const bool ok = ((unsigned)s < (unsigned)NS);
        const int sc = ok ? s : 0;
        // window = (1+cos(pi*d/2))/2 ; v_cos takes revolutions -> arg d/4
        const float c = __builtin_amdgcn_cosf((t - (float)s) * 0.25f);
        const float w = ok ? fmaf(0.5f, c, 0.5f) : 0.0f;

        const float w1v = W1[sc * NH + h];   // coalesced: h fast across lanes
        const float b1v = b1[sc * NH + h];
        const float w2v = W2[sc * NH + h];
        const float x = fmaf(t, w1v, b1v);
        const float e = __builtin_amdgcn_exp2f(x * C2L);          // e^(2x)
        const float r = __builtin_amdgcn_rcpf(e + 1.0f);
        // w2*tanh(x) = w2 - 2*w2*r
        partial = fmaf(w, fmaf(-2.0f * w2v, r, w2v), partial);
        wb2 = fmaf(w, b2[sc], wb2);
    }
    // reduce over the 32 h-lanes (xor<=16 stays within each 32-lane half)
    partial += __shfl_xor(partial, 1, 64);
    partial += __shfl_xor(partial, 2, 64);
    partial += __shfl_xor(partial, 4, 64);
    partial += __shfl_xor(partial, 8, 64);
    partial += __shfl_xor(partial, 16, 64);
    if (h == 0) table[g] = partial + wb2;
}

// Kernel B: per point, linear interpolation from the 16 KB (L1-resident) table.
__global__ __launch_bounds__(256) void interp_kernel(
    const float* __restrict__ t_in, const float* __restrict__ table,
    float* __restrict__ out, int N)
{
    const int n = blockIdx.x * 256 + threadIdx.x;
    if (n >= N) return;
    const float t = t_in[n];
    const float u = t * INV_STEP;
    int i = (int)u;
    i = min(max(i, 0), M_TAB - 1);
    const float f = u - (float)i;
    const float y0 = table[i];
    const float y1 = table[i + 1];
    out[n] = fmaf(f, y1 - y0, y0);
}

extern "C" void kernel_launch(void* const* d_in, const int* in_sizes, int n_in,
                              void* d_out, int out_size, void* d_ws, size_t ws_size,
                              hipStream_t stream) {
    const float* t  = (const float*)d_in[0];
    const float* W1 = (const float*)d_in[1];
    const float* b1 = (const float*)d_in[2];
    const float* W2 = (const float*)d_in[3];
    const float* b2 = (const float*)d_in[4];
    float* outp = (float*)d_out;
    const int N = in_sizes[0];

    float* table = (float*)d_ws;     // (M_TAB+1)*4 = 16388 B, rewritten each call

    const int blkA = ((M_TAB + 1) * NH + 255) / 256;   // 513 blocks
    table_kernel<<<blkA, 256, 0, stream>>>(W1, b1, W2, b2, table);
    interp_kernel<<<(N + 255) / 256, 256, 0, stream>>>(t, table, outp, N);
}